// Round 1
// baseline (5611.234 us; speedup 1.0000x reference)
//
#include <hip/hip_runtime.h>
#include <math.h>

// Problem constants (from reference setup_inputs): B=512, T=2048, D=10, H=20
#define BB 512
#define TT 2048
#define DD 10
#define HH 20
#define BH (BB*HH)          // 10240 elements per timestep

// ws layout (word indices from base)
#define WS_AMAX     0        // uint bits of maxabs(x), atomicMax target (memset to 0 first)
#define WS_PROD_XWI 4        // s_x * s_wi
#define WS_INV_SX   5
#define WS_S_H0     6
#define WS_INV_SH0  7
#define WS_S_WH     8
#define WS_BQ       16       // 20 floats: quantized bias
#define WS_WIP      40       // 60 ints: Wi levels packed int8x4, [j][3]
#define WS_WHP      104      // 100 ints: Wh levels packed int8x4, [j][5]
#define WS_XW_OFF   4096     // byte offset of xW / out_t buffer: [T][B][H] floats (84 MB)

__device__ __forceinline__ int dot4(int a, int b, int c) {
#if defined(__has_builtin)
#if __has_builtin(__builtin_amdgcn_sdot4)
    return __builtin_amdgcn_sdot4(a, b, c, false);
#define DOT4_DONE 1
#endif
#endif
#ifndef DOT4_DONE
    int r = c;
    r += ((a << 24) >> 24) * ((b << 24) >> 24);
    r += ((a << 16) >> 24) * ((b << 16) >> 24);
    r += ((a << 8) >> 24) * ((b << 8) >> 24);
    r += (a >> 24) * (b >> 24);
    return r;
#endif
}

// scale = exp2(ceil(log2(max(m,1e-10))))/128, exact via frexp; also returns 1/scale.
__device__ __forceinline__ float pow2scale(float m, float* inv) {
    m = fmaxf(m, 1e-10f);
    int e; float f = frexpf(m, &e);
    int k = (f == 0.5f) ? (e - 1) : e;   // ceil(log2(m))
    *inv = ldexpf(1.f, 7 - k);
    return ldexpf(1.f, k - 7);
}

__device__ __forceinline__ int qlevel(float v, float inv) {
    return (int)fminf(fmaxf(rintf(v * inv), -128.f), 127.f);
}

__device__ __forceinline__ int pack4(int a, int b, int c, int d) {
    return (a & 255) | ((b & 255) << 8) | ((c & 255) << 16) | ((d & 255) << 24);
}

// ---------------- kernel 1: maxabs(x) grid reduction -------------------------
__global__ void k_amax(const float* __restrict__ x, int n4, unsigned* amax) {
    int g = blockIdx.x * blockDim.x + threadIdx.x;
    int stride = gridDim.x * blockDim.x;
    const float4* xv = (const float4*)x;
    float m = 0.f;
    for (int i = g; i < n4; i += stride) {
        float4 v = xv[i];
        m = fmaxf(m, fmaxf(fmaxf(fabsf(v.x), fabsf(v.y)), fmaxf(fabsf(v.z), fabsf(v.w))));
    }
#pragma unroll
    for (int off = 32; off; off >>= 1) m = fmaxf(m, __shfl_xor(m, off, 64));
    if ((threadIdx.x & 63) == 0) atomicMax(amax, __float_as_uint(m));
}

// ---------------- kernel 2: scales + weight quant/pack -----------------------
__device__ float bmaxabs(const float* p, int n, float* red, int tid) {
    float m = 0.f;
    for (int i = tid; i < n; i += 256) m = fmaxf(m, fabsf(p[i]));
    red[tid] = m; __syncthreads();
    for (int s = 128; s; s >>= 1) {
        if (tid < s) red[tid] = fmaxf(red[tid], red[tid + s]);
        __syncthreads();
    }
    m = red[0]; __syncthreads();
    return m;
}

__global__ void k_prep(const float* __restrict__ Wi, const float* __restrict__ Wh,
                       const float* __restrict__ bias, const float* __restrict__ h0,
                       float* wsf, int* wsi) {
    __shared__ float red[256];
    __shared__ float hdr[4];
    int tid = threadIdx.x;
    float mwi = bmaxabs(Wi, HH * DD, red, tid);
    float mwh = bmaxabs(Wh, HH * HH, red, tid);
    float mb  = bmaxabs(bias, HH, red, tid);
    float mh0 = bmaxabs(h0, BH, red, tid);
    if (tid == 0) {
        float mx = __uint_as_float(((unsigned*)wsf)[WS_AMAX]);
        float isx, iswi, iswh, isb, ish0;
        float sx  = pow2scale(mx,  &isx);
        float swi = pow2scale(mwi, &iswi);
        float swh = pow2scale(mwh, &iswh);
        float sb  = pow2scale(mb,  &isb);
        float sh0 = pow2scale(mh0, &ish0);
        wsf[WS_PROD_XWI] = sx * swi;
        wsf[WS_INV_SX]   = isx;
        wsf[WS_S_H0]     = sh0;
        wsf[WS_INV_SH0]  = ish0;
        wsf[WS_S_WH]     = swh;
        hdr[0] = iswi; hdr[1] = iswh; hdr[2] = sb; hdr[3] = isb;
    }
    __syncthreads();
    if (tid < HH) {
        float iswi = hdr[0], iswh = hdr[1], sb = hdr[2], isb = hdr[3];
        int lv[20];
#pragma unroll
        for (int d = 0; d < DD; ++d) lv[d] = qlevel(Wi[tid * DD + d], iswi);
        lv[10] = 0; lv[11] = 0;
#pragma unroll
        for (int k = 0; k < 3; ++k)
            wsi[WS_WIP + tid * 3 + k] = pack4(lv[4*k], lv[4*k+1], lv[4*k+2], lv[4*k+3]);
#pragma unroll
        for (int k = 0; k < HH; ++k) lv[k] = qlevel(Wh[tid * HH + k], iswh);
#pragma unroll
        for (int k = 0; k < 5; ++k)
            wsi[WS_WHP + tid * 5 + k] = pack4(lv[4*k], lv[4*k+1], lv[4*k+2], lv[4*k+3]);
        wsf[WS_BQ + tid] = (float)qlevel(bias[tid], isb) * sb;
    }
}

// ---------------- kernel 3: xW[t][b][j] = quant(x)·Wi_q + bq -----------------
__global__ __launch_bounds__(256) void k_xw(const float* __restrict__ x,
                                            const float* __restrict__ wsf,
                                            const int* __restrict__ wsi,
                                            float* __restrict__ xw) {
    int g = blockIdx.x * 256 + threadIdx.x;    // g = b*T + t (lanes -> consecutive t)
    int t = g & (TT - 1);
    int b = g >> 11;
    float isx  = wsf[WS_INV_SX];
    float prod = wsf[WS_PROD_XWI];
    const float2* xp = (const float2*)(x + (size_t)g * DD);   // 8B-aligned (40B stride)
    float xv[10];
#pragma unroll
    for (int k = 0; k < 5; ++k) { float2 v = xp[k]; xv[2*k] = v.x; xv[2*k+1] = v.y; }
    int lv[12];
#pragma unroll
    for (int d = 0; d < DD; ++d) lv[d] = qlevel(xv[d], isx);
    lv[10] = 0; lv[11] = 0;
    int xpk[3];
#pragma unroll
    for (int k = 0; k < 3; ++k) xpk[k] = pack4(lv[4*k], lv[4*k+1], lv[4*k+2], lv[4*k+3]);
    float res[20];
#pragma unroll
    for (int j = 0; j < HH; ++j) {
        int ai = 0;
#pragma unroll
        for (int k = 0; k < 3; ++k) ai = dot4(xpk[k], wsi[WS_WIP + j * 3 + k], ai);
        res[j] = (float)ai * prod + wsf[WS_BQ + j];   // exact int scaled + single-round add
    }
    float4* op = (float4*)(xw + (size_t)t * BH + b * HH);     // 16B aligned
#pragma unroll
    for (int k = 0; k < 5; ++k)
        op[k] = make_float4(res[4*k], res[4*k+1], res[4*k+2], res[4*k+3]);
}

// ---------------- kernel 4: serial recurrence, 1 workgroup -------------------
// thread = (b, jhalf): b = tid>>1, j in [jh*10, jh*10+10). Wh int8-packed in 50 VGPRs.
// h state: int8 levels in LDS [512][20]. One min/max reduction per step gives BOTH
// the acc scale and (via tanh monotonicity + clip asymmetry) the h scale.
__global__ __launch_bounds__(1024) void k_rnn(const float* __restrict__ h0,
                                              const float* __restrict__ wsf,
                                              const int* __restrict__ wsi,
                                              float* __restrict__ xw) {
    __shared__ signed char hq[BH];
    __shared__ float wred[32];
    __shared__ float bc[8];
    __shared__ int lut[256];
    const int tid = threadIdx.x;
    const int b = tid >> 1;
    const int jb = (tid & 1) * 10;
    const float s_wh = wsf[WS_S_WH];
    float sprod = wsf[WS_S_H0] * s_wh;

    int whp[50];
#pragma unroll
    for (int jj = 0; jj < 10; ++jj)
#pragma unroll
        for (int k = 0; k < 5; ++k)
            whp[jj * 5 + k] = wsi[WS_WHP + (jb + jj) * 5 + k];

    {   // h0 -> levels
        float ish0 = wsf[WS_INV_SH0];
        const float* hp = h0 + b * HH + jb;
        int lv[10];
#pragma unroll
        for (int i = 0; i < 10; ++i) lv[i] = qlevel(hp[i], ish0);
#pragma unroll
        for (int k = 0; k < 5; ++k)
            *(short*)&hq[b * HH + jb + 2 * k] = (short)((lv[2*k] & 255) | ((lv[2*k+1] & 255) << 8));
    }
    float xwA[10];
    {   // preload xW for t=0
        const float2* p = (const float2*)(xw + b * HH + jb);
#pragma unroll
        for (int k = 0; k < 5; ++k) { float2 v = p[k]; xwA[2*k] = v.x; xwA[2*k+1] = v.y; }
    }
    __syncthreads();

    for (int t = 0; t < TT; ++t) {
        float xwB[10];
        if (t + 1 < TT) {   // prefetch next step's xW (hides HBM latency behind compute)
            const float2* p = (const float2*)(xw + (size_t)(t + 1) * BH + b * HH + jb);
#pragma unroll
            for (int k = 0; k < 5; ++k) { float2 v = p[k]; xwB[2*k] = v.x; xwB[2*k+1] = v.y; }
        }
        int hd[5];
        const int* hrow = (const int*)(hq + b * HH);   // 4B aligned, conflict-free (stride 5 mod 32)
#pragma unroll
        for (int k = 0; k < 5; ++k) hd[k] = hrow[k];
        float acc[10];
#pragma unroll
        for (int jj = 0; jj < 10; ++jj) {
            int ai = 0;
#pragma unroll
            for (int k = 0; k < 5; ++k) ai = dot4(hd[k], whp[jj * 5 + k], ai);
            acc[jj] = xwA[jj] + (float)ai * sprod;     // exact: int < 2^24, pow2 scale
        }
        // one (min,max) reduction -> both scales
        float mx = acc[0], mn = acc[0];
#pragma unroll
        for (int jj = 1; jj < 10; ++jj) { mx = fmaxf(mx, acc[jj]); mn = fminf(mn, acc[jj]); }
#pragma unroll
        for (int off = 32; off; off >>= 1) {
            mx = fmaxf(mx, __shfl_xor(mx, off, 64));
            mn = fminf(mn, __shfl_xor(mn, off, 64));
        }
        if ((tid & 63) == 0) { wred[tid >> 6] = mx; wred[16 + (tid >> 6)] = mn; }
        __syncthreads();
        if (tid == 0) {
            float ma = wred[0], mi = wred[16];
#pragma unroll
            for (int w = 1; w < 16; ++w) { ma = fmaxf(ma, wred[w]); mi = fminf(mi, wred[16 + w]); }
            float isa; float sa = pow2scale(fmaxf(ma, -mi), &isa);
            float lp = fminf(fmaxf(rintf(ma * isa), -128.f), 127.f);
            float ln = fminf(fmaxf(rintf(mi * isa), -128.f), 127.f);
            float mlvl = fmaxf(fabsf(lp), fabsf(ln));        // max |acc_q| / sa (clip asym incl.)
            float mh = tanhf(mlvl * sa);                     // max |h_new|
            float ish; float sh = pow2scale(mh, &ish);
            bc[0] = sa; bc[1] = isa; bc[2] = sh; bc[3] = ish; bc[4] = sh * s_wh;
        }
        __syncthreads();
        float sa = bc[0], isa = bc[1], sh = bc[2], ish = bc[3];
        sprod = bc[4];
        if (tid < 256) {   // per-step LUT: acc level -> quantized tanh level (exact tanhf)
            float tq = tanhf((float)(tid - 128) * sa);
            lut[tid] = (int)fminf(fmaxf(rintf(tq * ish), -128.f), 127.f);
        }
        __syncthreads();
        int ql[10];
#pragma unroll
        for (int jj = 0; jj < 10; ++jj) {
            int li = (int)fminf(fmaxf(rintf(acc[jj] * isa), -128.f), 127.f) + 128;
            ql[jj] = lut[li];
        }
        {   // write out[t][b][j] = level*sh, overwriting the consumed xW cell
            float2* op = (float2*)(xw + (size_t)t * BH + b * HH + jb);
#pragma unroll
            for (int k = 0; k < 5; ++k) {
                float2 v; v.x = (float)ql[2*k] * sh; v.y = (float)ql[2*k+1] * sh;
                op[k] = v;
            }
        }
#pragma unroll
        for (int k = 0; k < 5; ++k)
            *(short*)&hq[b * HH + jb + 2 * k] = (short)((ql[2*k] & 255) | ((ql[2*k+1] & 255) << 8));
#pragma unroll
        for (int jj = 0; jj < 10; ++jj) xwA[jj] = xwB[jj];
        __syncthreads();
    }
}

// ---------------- kernel 5: transpose [T][B][H] -> [B][T][H] -----------------
__global__ __launch_bounds__(256) void k_tr(const float* __restrict__ src, float* __restrict__ out) {
    __shared__ float tile[16 * 16 * HH];   // 20 KB
    int t0 = blockIdx.x * 16, b0 = blockIdx.y * 16;
    for (int i = threadIdx.x; i < 16 * 16 * HH; i += 256) {
        int r = i / (16 * HH), c = i % (16 * HH);
        tile[i] = src[(size_t)(t0 + r) * BH + b0 * HH + c];          // coalesced rows
    }
    __syncthreads();
    for (int i = threadIdx.x; i < 16 * 16 * HH; i += 256) {
        int bb = i / (16 * HH), rj = i % (16 * HH);
        int r = rj / HH, j = rj % HH;
        out[(size_t)(b0 + bb) * (TT * HH) + (t0 + r) * HH + j] = tile[r * (16 * HH) + bb * HH + j];
    }
}

extern "C" void kernel_launch(void* const* d_in, const int* in_sizes, int n_in,
                              void* d_out, int out_size, void* d_ws, size_t ws_size,
                              hipStream_t stream) {
    const float* x    = (const float*)d_in[0];
    const float* h0   = (const float*)d_in[1];
    const float* Wi   = (const float*)d_in[2];
    const float* Wh   = (const float*)d_in[3];
    const float* bias = (const float*)d_in[4];
    float* out = (float*)d_out;

    char* w = (char*)d_ws;
    float* wsf = (float*)w;
    int* wsi = (int*)w;
    unsigned* amax = (unsigned*)w;
    float* xw = (float*)(w + WS_XW_OFF);   // needs ~84 MB of ws

    hipMemsetAsync(d_ws, 0, 64, stream);   // zero atomicMax slot (ws is poisoned 0xAA)
    int n = in_sizes[0];
    k_amax<<<2048, 256, 0, stream>>>(x, n / 4, amax);
    k_prep<<<1, 256, 0, stream>>>(Wi, Wh, bias, h0, wsf, wsi);
    k_xw<<<(BB * TT) / 256, 256, 0, stream>>>(x, wsf, wsi, xw);
    k_rnn<<<1, 1024, 0, stream>>>(h0, wsf, wsi, xw);
    k_tr<<<dim3(TT / 16, BB / 16), 256, 0, stream>>>(xw, out);
}

// Round 2
// 5369.045 us; speedup vs baseline: 1.0451x; 1.0451x over previous
//
#include <hip/hip_runtime.h>
#include <math.h>

// Problem constants: B=512, T=2048, D=10, H=20
#define BB 512
#define TT 2048
#define DD 10
#define HH 20
#define BH (BB*HH)          // 10240 elements per timestep

// ws layout (word indices from base)
#define WS_AMAX     0
#define WS_PROD_XWI 4
#define WS_INV_SX   5
#define WS_S_H0     6
#define WS_INV_SH0  7
#define WS_S_WH     8
#define WS_BQ       16
#define WS_WIP      40
#define WS_WHP      104
#define WS_XW_OFF   4096     // byte offset of xW / out_t buffer: [T][B][H] floats (84 MB)

// LDS-only barrier: never drains vmcnt (prefetch loads / output stores stay in flight)
#define BAR() asm volatile("s_waitcnt lgkmcnt(0)\n\ts_barrier" ::: "memory")

__device__ __forceinline__ int dot4(int a, int b, int c) {
#if defined(__has_builtin)
#if __has_builtin(__builtin_amdgcn_sdot4)
    return __builtin_amdgcn_sdot4(a, b, c, false);
#define DOT4_DONE 1
#endif
#endif
#ifndef DOT4_DONE
    int r = c;
    r += ((a << 24) >> 24) * ((b << 24) >> 24);
    r += ((a << 16) >> 24) * ((b << 16) >> 24);
    r += ((a << 8) >> 24) * ((b << 8) >> 24);
    r += (a >> 24) * (b >> 24);
    return r;
#endif
}

// scale = exp2(ceil(log2(max(m,1e-10))))/128 via exponent bits (exact, branchless)
__device__ __forceinline__ void p2s(float m, float* s, float* is) {
    m = fmaxf(m, 1e-10f);
    unsigned u = __float_as_uint(m);
    int k = (int)(u >> 23) - 127 + ((u & 0x7fffffu) ? 1 : 0);  // ceil(log2(m))
    *s  = __uint_as_float((unsigned)(k + 120) << 23);           // 2^(k-7)
    *is = __uint_as_float((unsigned)(134 - k) << 23);           // 2^(7-k)
}

__device__ __forceinline__ int qlevel(float v, float inv) {
    return (int)fminf(fmaxf(rintf(v * inv), -128.f), 127.f);
}

__device__ __forceinline__ int pack4(int a, int b, int c, int d) {
    return (a & 255) | ((b & 255) << 8) | ((c & 255) << 16) | ((d & 255) << 24);
}

// ---------------- kernel 1: maxabs(x) grid reduction -------------------------
__global__ void k_amax(const float* __restrict__ x, int n4, unsigned* amax) {
    int g = blockIdx.x * blockDim.x + threadIdx.x;
    int stride = gridDim.x * blockDim.x;
    const float4* xv = (const float4*)x;
    float m = 0.f;
    for (int i = g; i < n4; i += stride) {
        float4 v = xv[i];
        m = fmaxf(m, fmaxf(fmaxf(fabsf(v.x), fabsf(v.y)), fmaxf(fabsf(v.z), fabsf(v.w))));
    }
#pragma unroll
    for (int off = 32; off; off >>= 1) m = fmaxf(m, __shfl_xor(m, off, 64));
    if ((threadIdx.x & 63) == 0) atomicMax(amax, __float_as_uint(m));
}

// ---------------- kernel 2: scales + weight quant/pack -----------------------
__device__ float bmaxabs(const float* p, int n, float* red, int tid) {
    float m = 0.f;
    for (int i = tid; i < n; i += 256) m = fmaxf(m, fabsf(p[i]));
    red[tid] = m; __syncthreads();
    for (int s = 128; s; s >>= 1) {
        if (tid < s) red[tid] = fmaxf(red[tid], red[tid + s]);
        __syncthreads();
    }
    m = red[0]; __syncthreads();
    return m;
}

__global__ void k_prep(const float* __restrict__ Wi, const float* __restrict__ Wh,
                       const float* __restrict__ bias, const float* __restrict__ h0,
                       float* wsf, int* wsi) {
    __shared__ float red[256];
    __shared__ float hdr[4];
    int tid = threadIdx.x;
    float mwi = bmaxabs(Wi, HH * DD, red, tid);
    float mwh = bmaxabs(Wh, HH * HH, red, tid);
    float mb  = bmaxabs(bias, HH, red, tid);
    float mh0 = bmaxabs(h0, BH, red, tid);
    if (tid == 0) {
        float mx = __uint_as_float(((unsigned*)wsf)[WS_AMAX]);
        float sx, isx, swi, iswi, swh, iswh, sb, isb, sh0, ish0;
        p2s(mx,  &sx,  &isx);
        p2s(mwi, &swi, &iswi);
        p2s(mwh, &swh, &iswh);
        p2s(mb,  &sb,  &isb);
        p2s(mh0, &sh0, &ish0);
        wsf[WS_PROD_XWI] = sx * swi;
        wsf[WS_INV_SX]   = isx;
        wsf[WS_S_H0]     = sh0;
        wsf[WS_INV_SH0]  = ish0;
        wsf[WS_S_WH]     = swh;
        hdr[0] = iswi; hdr[1] = iswh; hdr[2] = sb; hdr[3] = isb;
    }
    __syncthreads();
    if (tid < HH) {
        float iswi = hdr[0], iswh = hdr[1], sb = hdr[2], isb = hdr[3];
        int lv[20];
#pragma unroll
        for (int d = 0; d < DD; ++d) lv[d] = qlevel(Wi[tid * DD + d], iswi);
        lv[10] = 0; lv[11] = 0;
#pragma unroll
        for (int k = 0; k < 3; ++k)
            wsi[WS_WIP + tid * 3 + k] = pack4(lv[4*k], lv[4*k+1], lv[4*k+2], lv[4*k+3]);
#pragma unroll
        for (int k = 0; k < HH; ++k) lv[k] = qlevel(Wh[tid * HH + k], iswh);
#pragma unroll
        for (int k = 0; k < 5; ++k)
            wsi[WS_WHP + tid * 5 + k] = pack4(lv[4*k], lv[4*k+1], lv[4*k+2], lv[4*k+3]);
        wsf[WS_BQ + tid] = (float)qlevel(bias[tid], isb) * sb;
    }
}

// ---------------- kernel 3: xW[t][b][j] = quant(x)·Wi_q + bq -----------------
// lane dim = b  ->  writes to [t][b*20..] are contiguous across lanes (coalesced)
__global__ __launch_bounds__(256) void k_xw(const float* __restrict__ x,
                                            const float* __restrict__ wsf,
                                            const int* __restrict__ wsi,
                                            float* __restrict__ xw) {
    int g = blockIdx.x * 256 + threadIdx.x;
    int b = g & (BB - 1);
    int t = g >> 9;
    float isx  = wsf[WS_INV_SX];
    float prod = wsf[WS_PROD_XWI];
    const float2* xp = (const float2*)(x + ((size_t)b * TT + t) * DD);  // 8B-aligned
    float xv[10];
#pragma unroll
    for (int k = 0; k < 5; ++k) { float2 v = xp[k]; xv[2*k] = v.x; xv[2*k+1] = v.y; }
    int lv[12];
#pragma unroll
    for (int d = 0; d < DD; ++d) lv[d] = qlevel(xv[d], isx);
    lv[10] = 0; lv[11] = 0;
    int xpk[3];
#pragma unroll
    for (int k = 0; k < 3; ++k) xpk[k] = pack4(lv[4*k], lv[4*k+1], lv[4*k+2], lv[4*k+3]);
    float res[20];
#pragma unroll
    for (int j = 0; j < HH; ++j) {
        int ai = 0;
#pragma unroll
        for (int k = 0; k < 3; ++k) ai = dot4(xpk[k], wsi[WS_WIP + j * 3 + k], ai);
        res[j] = (float)ai * prod + wsf[WS_BQ + j];
    }
    float4* op = (float4*)(xw + (size_t)t * BH + b * HH);   // 80B/thread, coalesced
#pragma unroll
    for (int k = 0; k < 5; ++k)
        op[k] = make_float4(res[4*k], res[4*k+1], res[4*k+2], res[4*k+3]);
}

// ---------------- kernel 4: serial recurrence, 1 workgroup -------------------
// thread = (b, jhalf). h levels live in registers; the pair exchanges packed
// levels via shfl_xor(1) (intra-wave). 2 raw barriers/step, no vmcnt drains.
__global__ __launch_bounds__(1024) void k_rnn(const float* __restrict__ h0,
                                              const float* __restrict__ wsf,
                                              const int* __restrict__ wsi,
                                              float* __restrict__ xw) {
    __shared__ float2 wred[16];
    __shared__ float4 bc;
    __shared__ int lut[256];
    const int tid = threadIdx.x;
    const int b = tid >> 1;
    const int jb = (tid & 1) * 10;
    const bool isLo = (tid & 1) == 0;
    const float s_wh = wsf[WS_S_WH];
    float sprod = wsf[WS_S_H0] * s_wh;

    int whp[50];
#pragma unroll
    for (int jj = 0; jj < 10; ++jj)
#pragma unroll
        for (int k = 0; k < 5; ++k)
            whp[jj * 5 + k] = wsi[WS_WHP + (jb + jj) * 5 + k];

    int hd[5];
    {   // h0 -> levels -> pack -> pair exchange -> full row in hd[5]
        float ish0 = wsf[WS_INV_SH0];
        const float2* hp = (const float2*)(h0 + b * HH + jb);
        int lv[10];
#pragma unroll
        for (int k = 0; k < 5; ++k) {
            float2 v = hp[k];
            lv[2*k]   = qlevel(v.x, ish0);
            lv[2*k+1] = qlevel(v.y, ish0);
        }
        int PA = pack4(lv[0], lv[1], lv[2], lv[3]);
        int PB = pack4(lv[4], lv[5], lv[6], lv[7]);
        int PC = (lv[8] & 255) | ((lv[9] & 255) << 8);
        int QA = __shfl_xor(PA, 1, 64);
        int QB = __shfl_xor(PB, 1, 64);
        int QC = __shfl_xor(PC, 1, 64);
        int XA = isLo ? PA : QA, XB = isLo ? PB : QB, XC = isLo ? PC : QC;
        int YA = isLo ? QA : PA, YB = isLo ? QB : PB, YC = isLo ? QC : PC;
        hd[0] = XA; hd[1] = XB;
        hd[2] = (XC & 0xFFFF) | (YA << 16);
        hd[3] = ((unsigned)YA >> 16) | (YB << 16);
        hd[4] = ((unsigned)YB >> 16) | (YC << 16);
    }
    float xwA[10];
    {
        const float2* p = (const float2*)(xw + b * HH + jb);
#pragma unroll
        for (int k = 0; k < 5; ++k) { float2 v = p[k]; xwA[2*k] = v.x; xwA[2*k+1] = v.y; }
    }

    for (int t = 0; t < TT; ++t) {
        float xwB[10];
        if (t + 1 < TT) {   // prefetch next step (stays in flight across barriers)
            const float2* p = (const float2*)(xw + (size_t)(t + 1) * BH + b * HH + jb);
#pragma unroll
            for (int k = 0; k < 5; ++k) { float2 v = p[k]; xwB[2*k] = v.x; xwB[2*k+1] = v.y; }
        }
        float acc[10];
#pragma unroll
        for (int jj = 0; jj < 10; ++jj) {
            int ai = 0;
#pragma unroll
            for (int k = 0; k < 5; ++k) ai = dot4(hd[k], whp[jj * 5 + k], ai);
            acc[jj] = xwA[jj] + (float)ai * sprod;   // exact: |ai| < 2^24, pow2 scale
        }
        // per-wave (max, max-of-negative) reduction
        float mx = acc[0], nmi = -acc[0];
#pragma unroll
        for (int jj = 1; jj < 10; ++jj) { mx = fmaxf(mx, acc[jj]); nmi = fmaxf(nmi, -acc[jj]); }
#pragma unroll
        for (int off = 32; off; off >>= 1) {
            mx  = fmaxf(mx,  __shfl_xor(mx,  off, 64));
            nmi = fmaxf(nmi, __shfl_xor(nmi, off, 64));
        }
        if ((tid & 63) == 0) wred[tid >> 6] = make_float2(mx, nmi);
        BAR();   // B1
        float isa, sh;
        float sprodN;
        if (tid < 256) {   // waves 0-3: cross-wave reduce + scales (redundant) + LUT
            float2 p = wred[tid & 15];
            float ma = p.x, nm = p.y;
#pragma unroll
            for (int off = 8; off; off >>= 1) {
                ma = fmaxf(ma, __shfl_xor(ma, off, 64));
                nm = fmaxf(nm, __shfl_xor(nm, off, 64));
            }
            float sa;
            p2s(fmaxf(ma, nm), &sa, &isa);
            float lp = fminf(fmaxf(rintf(ma * isa), -128.f), 127.f);
            float ln = fminf(fmaxf(rintf(-nm * isa), -128.f), 127.f);
            float mlvl = fmaxf(fabsf(lp), fabsf(ln));   // max |acc_q| (clip asym incl.)
            float mh = tanhf(mlvl * sa);                // max |h_new| (tanh monotone)
            float ish;
            p2s(mh, &sh, &ish);
            sprodN = sh * s_wh;
            float tq = tanhf((float)(tid - 128) * sa);  // LUT: acc level -> h level
            lut[tid] = (int)fminf(fmaxf(rintf(tq * ish), -128.f), 127.f);
            if (tid == 0) bc = make_float4(isa, sh, sprodN, 0.f);
        }
        BAR();   // B2
        if (tid >= 256) {
            float4 v = bc;
            isa = v.x; sh = v.y; sprod = v.z;
        } else {
            sprod = sprodN;
        }
        int ql[10];
#pragma unroll
        for (int jj = 0; jj < 10; ++jj) {
            int qi = (int)fminf(fmaxf(rintf(acc[jj] * isa), -128.f), 127.f);
            ql[jj] = lut[128 + qi];
        }
        {   // write out[t][b][j] = level*sh (fire-and-forget, drained lazily)
            float2* op = (float2*)(xw + (size_t)t * BH + b * HH + jb);
#pragma unroll
            for (int k = 0; k < 5; ++k)
                op[k] = make_float2((float)ql[2*k] * sh, (float)ql[2*k+1] * sh);
        }
        {   // new h levels -> pack -> pair exchange -> hd[5]
            int PA = pack4(ql[0], ql[1], ql[2], ql[3]);
            int PB = pack4(ql[4], ql[5], ql[6], ql[7]);
            int PC = (ql[8] & 255) | ((ql[9] & 255) << 8);
            int QA = __shfl_xor(PA, 1, 64);
            int QB = __shfl_xor(PB, 1, 64);
            int QC = __shfl_xor(PC, 1, 64);
            int XA = isLo ? PA : QA, XB = isLo ? PB : QB, XC = isLo ? PC : QC;
            int YA = isLo ? QA : PA, YB = isLo ? QB : PB, YC = isLo ? QC : PC;
            hd[0] = XA; hd[1] = XB;
            hd[2] = (XC & 0xFFFF) | (YA << 16);
            hd[3] = ((unsigned)YA >> 16) | (YB << 16);
            hd[4] = ((unsigned)YB >> 16) | (YC << 16);
        }
#pragma unroll
        for (int jj = 0; jj < 10; ++jj) xwA[jj] = xwB[jj];
    }
}

// ---------------- kernel 5: transpose [T][B][H] -> [B][T][H] -----------------
__global__ __launch_bounds__(256) void k_tr(const float* __restrict__ src, float* __restrict__ out) {
    __shared__ float tile[16 * 16 * HH];   // 20 KB
    int t0 = blockIdx.x * 16, b0 = blockIdx.y * 16;
    for (int i = threadIdx.x; i < 16 * 16 * HH; i += 256) {
        int r = i / (16 * HH), c = i % (16 * HH);
        tile[i] = src[(size_t)(t0 + r) * BH + b0 * HH + c];
    }
    __syncthreads();
    for (int i = threadIdx.x; i < 16 * 16 * HH; i += 256) {
        int bb = i / (16 * HH), rj = i % (16 * HH);
        int r = rj / HH, j = rj % HH;
        out[(size_t)(b0 + bb) * (TT * HH) + (t0 + r) * HH + j] = tile[r * (16 * HH) + bb * HH + j];
    }
}

extern "C" void kernel_launch(void* const* d_in, const int* in_sizes, int n_in,
                              void* d_out, int out_size, void* d_ws, size_t ws_size,
                              hipStream_t stream) {
    const float* x    = (const float*)d_in[0];
    const float* h0   = (const float*)d_in[1];
    const float* Wi   = (const float*)d_in[2];
    const float* Wh   = (const float*)d_in[3];
    const float* bias = (const float*)d_in[4];
    float* out = (float*)d_out;

    char* w = (char*)d_ws;
    float* wsf = (float*)w;
    int* wsi = (int*)w;
    unsigned* amax = (unsigned*)w;
    float* xw = (float*)(w + WS_XW_OFF);

    hipMemsetAsync(d_ws, 0, 64, stream);
    int n = in_sizes[0];
    k_amax<<<2048, 256, 0, stream>>>(x, n / 4, amax);
    k_prep<<<1, 256, 0, stream>>>(Wi, Wh, bias, h0, wsf, wsi);
    k_xw<<<(BB * TT) / 256, 256, 0, stream>>>(x, wsf, wsi, xw);
    k_rnn<<<1, 1024, 0, stream>>>(h0, wsf, wsi, xw);
    k_tr<<<dim3(TT / 16, BB / 16), 256, 0, stream>>>(xw, out);
}